// Round 2
// baseline (68.055 us; speedup 1.0000x reference)
//
#include <hip/hip_runtime.h>

#define THREADS 256
#define QPB 2            // queries per block
#define KNN 32
#define CAP 512          // candidate buffer capacity (typical Ccnt ~ 36)
#define NBIN 256
#define BINBASE 0x790    // (float bits of 2^-6) >> 19

constexpr int Bc = 4, Nc = 8192, Sc = 2048, Cch = 64;

__global__ __launch_bounds__(THREADS) void neighbor_group_kernel(
    const float* __restrict__ xyz,      // (B, N, 3)
    const float* __restrict__ new_xyz,  // (B, S, 3)
    const float* __restrict__ feat,     // (B, N, C)
    float* __restrict__ out)
{
  __shared__ unsigned hist[QPB][NBIN];
  __shared__ unsigned candDb[QPB][CAP];
  __shared__ unsigned candIdx[QPB][CAP];
  __shared__ unsigned winIdx[QPB][KNN];
  __shared__ unsigned winDb[QPB][KNN];
  __shared__ unsigned ccnt[QPB];
  __shared__ unsigned sEdge[QPB];
  __shared__ unsigned wsum[4];

  const int tid = threadIdx.x;
  const int q0 = blockIdx.x * QPB;
  const int b = q0 >> 11;              // / S (S = 2048), QPB queries share a batch

  // zero histograms / counters
  ((unsigned*)hist)[tid] = 0u;
  ((unsigned*)hist)[tid + THREADS] = 0u;
  if (tid < QPB) ccnt[tid] = 0u;
  __syncthreads();

  float qx[QPB], qy[QPB], qz[QPB];
#pragma unroll
  for (int qi = 0; qi < QPB; ++qi) {
    qx[qi] = new_xyz[(q0 + qi) * 3 + 0];
    qy[qi] = new_xyz[(q0 + qi) * 3 + 1];
    qz[qi] = new_xyz[(q0 + qi) * 3 + 2];
  }

  const float4* __restrict__ xb4 = (const float4*)(xyz + (size_t)b * Nc * 3);

  // dist^2 bits, bit-exact vs numpy (no FMA contraction); sqrt deferred
  unsigned keys[QPB][32];

#pragma unroll
  for (int j2 = 0; j2 < 8; ++j2) {
    const int g = tid + j2 * THREADS;       // group of 4 consecutive points
    const float4 f0 = xb4[3 * g + 0];
    const float4 f1 = xb4[3 * g + 1];
    const float4 f2 = xb4[3 * g + 2];
    const float px[4] = {f0.x, f0.w, f1.z, f2.y};
    const float py[4] = {f0.y, f1.x, f1.w, f2.z};
    const float pz[4] = {f0.z, f1.y, f2.x, f2.w};
#pragma unroll
    for (int k = 0; k < 4; ++k) {
#pragma unroll
      for (int qi = 0; qi < QPB; ++qi) {
        const float dx = __fsub_rn(qx[qi], px[k]);
        const float dy = __fsub_rn(qy[qi], py[k]);
        const float dz = __fsub_rn(qz[qi], pz[k]);
        const float s2 = __fadd_rn(
            __fadd_rn(__fmul_rn(dx, dx), __fmul_rn(dy, dy)),
            __fmul_rn(dz, dz));
        const unsigned kb = __float_as_uint(s2);
        keys[qi][j2 * 4 + k] = kb;
        const int bin = min(255, max(0, (int)(kb >> 19) - BINBASE));
        atomicAdd(&hist[qi][bin], 1u);
      }
    }
  }
  __syncthreads();

  // prefix-scan each histogram; find bin where cumulative count crosses KNN
#pragma unroll
  for (int qi = 0; qi < QPB; ++qi) {
    const unsigned h = hist[qi][tid];
    unsigned v = h;
#pragma unroll
    for (int m = 1; m < 64; m <<= 1) {
      const unsigned u = (unsigned)__shfl_up((int)v, m, 64);
      if ((tid & 63) >= m) v += u;
    }
    if ((tid & 63) == 63) wsum[tid >> 6] = v;
    __syncthreads();
    unsigned off = 0;
    for (int w = 0; w < (tid >> 6); ++w) off += wsum[w];
    const unsigned cum = v + off;                 // inclusive
    if (cum >= KNN && (cum - h) < KNN) {          // unique crossing bin
      sEdge[qi] = (unsigned)(BINBASE + tid + 1) << 19;
    }
    __syncthreads();
  }

  // compact candidates (dist^2 bits below bin edge) to LDS
#pragma unroll
  for (int qi = 0; qi < QPB; ++qi) {
    const unsigned edge = sEdge[qi];
#pragma unroll
    for (int j = 0; j < 32; ++j) {
      if (keys[qi][j] < edge) {
        const unsigned pos = atomicAdd(&ccnt[qi], 1u);
        if (pos < CAP) {
          candDb[qi][pos] = keys[qi][j];
          // point index: p = 4*tid + (j>>2)*1024 + (j&3)
          candIdx[qi][pos] = (unsigned)(4 * tid + (j >> 2) * 1024 + (j & 3));
        }
      }
    }
  }
  __syncthreads();

  // sqrt only the candidates (ranking key must be sqrt bits for numpy ties)
#pragma unroll
  for (int qi = 0; qi < QPB; ++qi) {
    const unsigned Cc = min(ccnt[qi], (unsigned)CAP);
    for (unsigned t = tid; t < Cc; t += THREADS)
      candDb[qi][t] =
          __float_as_uint(__fsqrt_rn(__uint_as_float(candDb[qi][t])));
  }
  __syncthreads();

  // exact rank by (sqrt bits, idx) lexicographic; ranks unique
#pragma unroll
  for (int qi = 0; qi < QPB; ++qi) {
    const unsigned Cc = min(ccnt[qi], (unsigned)CAP);
    for (unsigned t = tid; t < Cc; t += THREADS) {
      const unsigned mdb = candDb[qi][t];
      const unsigned mix = candIdx[qi][t];
      unsigned rank = 0;
      for (unsigned o = 0; o < Cc; ++o) {
        const unsigned odb = candDb[qi][o];
        const unsigned oix = candIdx[qi][o];
        rank += (odb < mdb || (odb == mdb && oix < mix)) ? 1u : 0u;
      }
      if (rank < KNN) { winIdx[qi][rank] = mix; winDb[qi][rank] = mdb; }
    }
  }
  __syncthreads();

  // outputs (flat concat: nxyz | idxs | nfeat | values), all read back as f32
  float* out_nx = out;                                   // B*S*K*3
  float* out_id = out + (size_t)Bc * Sc * KNN * 3;       // B*S*K
  float* out_nf = out_id + (size_t)Bc * Sc * KNN;        // B*S*K*C
  float* out_sv = out_nf + (size_t)Bc * Sc * KNN * Cch;  // B*S*K

  const float* xb = xyz + (size_t)b * Nc * 3;
  const float4* fb4 = (const float4*)(feat + (size_t)b * Nc * Cch);

#pragma unroll
  for (int qi = 0; qi < QPB; ++qi) {
    const int q = q0 + qi;
    if (tid < KNN) {
      out_id[(size_t)q * KNN + tid] = (float)winIdx[qi][tid];
      out_sv[(size_t)q * KNN + tid] = __uint_as_float(winDb[qi][tid]);
    }
    if (tid < KNN * 3) {
      const int w = tid / 3, c3 = tid % 3;
      out_nx[((size_t)q * KNN + w) * 3 + c3] =
          xb[(size_t)winIdx[qi][w] * 3 + c3];
    }
    // feature gather, float4 rows (64 floats = 16 float4 per winner)
    float4* onf4 = (float4*)(out_nf + (size_t)q * KNN * Cch);
#pragma unroll
    for (int r = 0; r < 2; ++r) {
      const int flat = tid + r * THREADS;   // 0..511
      const int w = flat >> 4;              // winner 0..31
      const int c4 = flat & 15;
      onf4[w * 16 + c4] = fb4[(size_t)winIdx[qi][w] * 16 + c4];
    }
  }
}

extern "C" void kernel_launch(void* const* d_in, const int* in_sizes, int n_in,
                              void* d_out, int out_size, void* d_ws, size_t ws_size,
                              hipStream_t stream) {
  const float* xyz     = (const float*)d_in[0];
  const float* new_xyz = (const float*)d_in[1];
  const float* feat    = (const float*)d_in[2];
  float* out = (float*)d_out;

  const int grid = (Bc * Sc) / QPB;  // 4096 blocks, 2 queries each
  neighbor_group_kernel<<<grid, THREADS, 0, stream>>>(xyz, new_xyz, feat, out);
}